// Round 2
// baseline (78.446 us; speedup 1.0000x reference)
//
#include <hip/hip_runtime.h>
#include <hip/hip_bf16.h>

// Problem sizes (fixed by the reference)
#define S_LEN 256     // sequence length (t)
#define DM    512     // d_model (k / d)
#define DR    512     // d_rnn (s)
// d_in: x(256*512) f32, state(512*512) f32, W1(1024*512) f32, b1(1024) f32, Lambda(512) f32
// d_out: FLOAT32 (reference output dtype): y(256*512*512) then state(512*512)

// ws layout (floats):
//   xT   : [512][256]              at 0        (131072)
//   part : [2][1024][256]          at 131072   (524288)
//   aT   : [512][256]              at 655360   (131072)
//   cT   : [512][256]              at 786432   (131072)

__global__ __launch_bounds__(256) void k_transpose_x(const float* __restrict__ x,
                                                     float* __restrict__ xT) {
    __shared__ float tile[32][33];
    const int k0 = blockIdx.x * 32;          // over DM=512
    const int t0 = blockIdx.y * 32;          // over S=256
    const int lx = threadIdx.x & 31;
    const int ly = threadIdx.x >> 5;         // 0..7
#pragma unroll
    for (int i = 0; i < 32; i += 8)
        tile[ly + i][lx] = x[(t0 + ly + i) * DM + k0 + lx];
    __syncthreads();
#pragma unroll
    for (int i = 0; i < 32; i += 8)
        xT[(k0 + ly + i) * S_LEN + t0 + lx] = tile[lx][ly + i];
}

// grid (128, 2): blockIdx.x = n-group of 8 rows of W1, blockIdx.y = K-split half
__global__ __launch_bounds__(256) void k_gemm(const float* __restrict__ xT,
                                              const float* __restrict__ W1,
                                              float* __restrict__ part) {
    const int ng = blockIdx.x;       // 0..127 -> n = ng*8 .. ng*8+7
    const int ks = blockIdx.y;       // 0..1
    const int t  = threadIdx.x;      // 0..255 (lane axis = t, coalesced)
    const int k0 = ks * 256;

    float acc[8] = {0.f, 0.f, 0.f, 0.f, 0.f, 0.f, 0.f, 0.f};
    const float* __restrict__ wb = W1 + (ng * 8) * DM + k0;   // wave-uniform (scalar loads)
    const float* __restrict__ xb = xT + k0 * S_LEN + t;

#pragma unroll 8
    for (int k = 0; k < 256; ++k) {
        const float xv = xb[k * S_LEN];
#pragma unroll
        for (int j = 0; j < 8; ++j)
            acc[j] = fmaf(xv, wb[j * DM + k], acc[j]);
    }

    float* __restrict__ pb = part + ks * (1024 * 256) + (ng * 8) * 256 + t;
#pragma unroll
    for (int j = 0; j < 8; ++j) pb[j * 256] = acc[j];
}

// grid (512): one block per s; threads = t. Produces aT[s][t], cT[s][t].
__global__ __launch_bounds__(256) void k_act(const float* __restrict__ part,
                                             const float* __restrict__ b1,
                                             const float* __restrict__ Lam,
                                             float* __restrict__ aT,
                                             float* __restrict__ cT) {
    const int s = blockIdx.x;
    const int t = threadIdx.x;
    const int P2 = 1024 * 256;

    const float pre_i = part[s * 256 + t] + part[P2 + s * 256 + t] + b1[s];
    const float pre_r = part[(512 + s) * 256 + t] + part[P2 + (512 + s) * 256 + t] + b1[512 + s];

    const float inp = 1.f / (1.f + expf(-pre_i));    // sigmoid
    const float rec = 1.f / (1.f + expf(-pre_r));    // sigmoid
    const float sp  = log1pf(expf(Lam[s]));          // softplus
    const float a   = expf(-8.f * sp * rec);
    const float c   = sqrtf(fmaxf(1.f - a * a, 0.f)) * inp;

    aT[s * 256 + t] = a;
    cT[s * 256 + t] = c;
}

// grid (512): one block per s. Thread handles d0=2*tid, d0+1. Streams y in f32.
__global__ __launch_bounds__(256) void k_rec(const float* __restrict__ x,
                                             const float* __restrict__ state0,
                                             const float* __restrict__ aT,
                                             const float* __restrict__ cT,
                                             float2* __restrict__ out2) {
    const int s   = blockIdx.x;
    const int tid = threadIdx.x;

    __shared__ float a_l[256];
    __shared__ float c_l[256];
    a_l[tid] = aT[s * 256 + tid];
    c_l[tid] = cT[s * 256 + tid];
    __syncthreads();

    const float2* __restrict__ st2 = reinterpret_cast<const float2*>(state0);
    float2 h = st2[s * 256 + tid];

    const float2* __restrict__ x2 = reinterpret_cast<const float2*>(x);

#pragma unroll 8
    for (int t = 0; t < S_LEN; ++t) {
        const float at = a_l[t];
        const float ct = c_l[t];
        const float2 xv = x2[t * 256 + tid];
        h.x = fmaf(at, h.x, ct * xv.x);
        h.y = fmaf(at, h.y, ct * xv.y);
        out2[t * (DR * DM / 2) + s * 256 + tid] = h;   // y[t][s][d0..d0+1]
    }
    // final state = h after t=255
    out2[(S_LEN * DR * DM / 2) + s * 256 + tid] = h;
}

extern "C" void kernel_launch(void* const* d_in, const int* in_sizes, int n_in,
                              void* d_out, int out_size, void* d_ws, size_t ws_size,
                              hipStream_t stream) {
    const float* x      = (const float*)d_in[0];
    const float* state0 = (const float*)d_in[1];
    const float* W1     = (const float*)d_in[2];
    const float* b1     = (const float*)d_in[3];
    const float* Lam    = (const float*)d_in[4];

    float* ws   = (float*)d_ws;
    float* xT   = ws;                 // 131072 floats
    float* part = ws + 131072;        // 524288 floats
    float* aT   = ws + 655360;        // 131072 floats
    float* cT   = ws + 786432;        // 131072 floats

    float2* out2 = (float2*)d_out;

    k_transpose_x<<<dim3(16, 8), 256, 0, stream>>>(x, xT);
    k_gemm<<<dim3(128, 2), 256, 0, stream>>>(xT, W1, part);
    k_act<<<dim3(512), 256, 0, stream>>>(part, b1, Lam, aT, cT);
    k_rec<<<dim3(512), 256, 0, stream>>>(x, state0, aT, cT, out2);
}

// Round 4
// 74.484 us; speedup vs baseline: 1.0532x; 1.0532x over previous
//
#include <hip/hip_runtime.h>
#include <hip/hip_bf16.h>

// Problem sizes (fixed by the reference)
#define S_LEN 256     // sequence length (t)
#define DM    512     // d_model (k / d)
#define DR    512     // d_rnn (s)
// d_in: x(256*512) f32, state(512*512) f32, W1(1024*512) f32, b1(1024) f32, Lambda(512) f32
// d_out: f32: y(256*512*512) then state(512*512)

// Native 16B vector (HIP's float4 is a class — rejected by nontemporal builtin)
typedef float f4 __attribute__((ext_vector_type(4)));
typedef float f2 __attribute__((ext_vector_type(2)));

// ws layout (floats):
//   xT  : [512][256]          at 0       (131072 floats)
//   acT : f2[512][256]        at 131072  (262144 floats)

__global__ __launch_bounds__(256) void k_transpose_x(const float* __restrict__ x,
                                                     float* __restrict__ xT) {
    __shared__ float tile[32][33];
    const int k0 = blockIdx.x * 32;          // over DM=512
    const int t0 = blockIdx.y * 32;          // over S=256
    const int lx = threadIdx.x & 31;
    const int ly = threadIdx.x >> 5;         // 0..7
#pragma unroll
    for (int i = 0; i < 32; i += 8)
        tile[ly + i][lx] = x[(t0 + ly + i) * DM + k0 + lx];
    __syncthreads();
#pragma unroll
    for (int i = 0; i < 32; i += 8)
        xT[(k0 + ly + i) * S_LEN + t0 + lx] = tile[lx][ly + i];
}

// grid(256): block g computes GEMM rows {2g, 2g+1, 512+2g, 512+2g+1} over all t,
// then applies sigmoid/softplus/exp epilogue and writes acT[s][t] = {a, c}.
__global__ __launch_bounds__(256) void k_gemm_act(const float* __restrict__ xT,
                                                  const float* __restrict__ W1,
                                                  const float* __restrict__ b1,
                                                  const float* __restrict__ Lam,
                                                  f2* __restrict__ acT) {
    const int g  = blockIdx.x;       // 0..255
    const int t  = threadIdx.x;      // 0..255 (lane axis = t, coalesced xT loads)
    const int r0 = 2 * g;            // s rows r0, r0+1

    float acc0 = 0.f, acc1 = 0.f, acc2 = 0.f, acc3 = 0.f;
    const float* __restrict__ xb = xT + t;
    const float* __restrict__ w0 = W1 + (r0)       * DM;   // wave-uniform → s_loads
    const float* __restrict__ w1 = W1 + (r0 + 1)   * DM;
    const float* __restrict__ w2 = W1 + (512 + r0) * DM;
    const float* __restrict__ w3 = W1 + (513 + r0) * DM;

#pragma unroll 8
    for (int k = 0; k < DM; ++k) {
        const float xv = xb[k * S_LEN];
        acc0 = fmaf(xv, w0[k], acc0);
        acc1 = fmaf(xv, w1[k], acc1);
        acc2 = fmaf(xv, w2[k], acc2);
        acc3 = fmaf(xv, w3[k], acc3);
    }

#pragma unroll
    for (int j = 0; j < 2; ++j) {
        const float pre_i = (j ? acc1 : acc0) + b1[r0 + j];
        const float pre_r = (j ? acc3 : acc2) + b1[512 + r0 + j];
        const float inp = 1.f / (1.f + expf(-pre_i));     // sigmoid
        const float rec = 1.f / (1.f + expf(-pre_r));     // sigmoid
        const float sp  = log1pf(expf(Lam[r0 + j]));      // softplus
        const float a   = expf(-8.f * sp * rec);
        const float c   = sqrtf(fmaxf(1.f - a * a, 0.f)) * inp;
        f2 ac; ac.x = a; ac.y = c;
        acT[(r0 + j) * S_LEN + t] = ac;
    }
}

// grid(256) x 256 threads: block covers s = {2*bx, 2*bx+1}; thread handles 4 d
// (f4). Streams y with nontemporal dwordx4 stores.
__global__ __launch_bounds__(256) void k_rec(const float* __restrict__ x,
                                             const float* __restrict__ state0,
                                             const f2* __restrict__ acT,
                                             f4* __restrict__ out4) {
    const int bx   = blockIdx.x;
    const int tid  = threadIdx.x;
    const int half = tid >> 7;           // 0 or 1
    const int s    = bx * 2 + half;
    const int dq   = tid & 127;          // d/4

    __shared__ f2 ac_l[2][S_LEN];        // {a, c} per (half, t)
    f2* lf = &ac_l[0][0];
    lf[tid]       = acT[bx * 2 * S_LEN + tid];
    lf[tid + 256] = acT[bx * 2 * S_LEN + tid + 256];
    __syncthreads();

    const f4* __restrict__ st4 = reinterpret_cast<const f4*>(state0);
    f4 h = st4[s * 128 + dq];

    const f4* __restrict__ x4 = reinterpret_cast<const f4*>(x);
    f4 xv = x4[dq];                      // t = 0 prefetch

#pragma unroll 4
    for (int t = 0; t < S_LEN; ++t) {
        f4 xn;
        if (t + 1 < S_LEN) xn = x4[(t + 1) * 128 + dq];
        else xn = (f4)0.f;

        const f2 ac = ac_l[half][t];               // LDS broadcast (wave-uniform)
        const float at = ac.x, ct = ac.y;
        h.x = fmaf(at, h.x, ct * xv.x);
        h.y = fmaf(at, h.y, ct * xv.y);
        h.z = fmaf(at, h.z, ct * xv.z);
        h.w = fmaf(at, h.w, ct * xv.w);

        __builtin_nontemporal_store(h, &out4[(t * DR + s) * 128 + dq]);
        xv = xn;
    }
    // final state
    out4[(S_LEN * DR) * 128 + s * 128 + dq] = h;
}

extern "C" void kernel_launch(void* const* d_in, const int* in_sizes, int n_in,
                              void* d_out, int out_size, void* d_ws, size_t ws_size,
                              hipStream_t stream) {
    const float* x      = (const float*)d_in[0];
    const float* state0 = (const float*)d_in[1];
    const float* W1     = (const float*)d_in[2];
    const float* b1     = (const float*)d_in[3];
    const float* Lam    = (const float*)d_in[4];

    float* ws  = (float*)d_ws;
    float* xT  = ws;                      // 131072 floats
    f2*    acT = (f2*)(ws + 131072);      // 131072 f2

    f4* out4 = (f4*)d_out;

    k_transpose_x<<<dim3(16, 8), 256, 0, stream>>>(x, xT);
    k_gemm_act<<<dim3(256), 256, 0, stream>>>(xT, W1, b1, Lam, acT);
    k_rec<<<dim3(256), 256, 0, stream>>>(x, state0, acT, out4);
}